// Round 2
// baseline (1335.848 us; speedup 1.0000x reference)
//
#include <hip/hip_runtime.h>
#include <hip/hip_bf16.h>

typedef __attribute__((ext_vector_type(8))) short short8;
typedef __attribute__((ext_vector_type(4))) float f32x4;

#define GLDS16(g, l)                                                     \
  __builtin_amdgcn_global_load_lds(                                      \
      (const __attribute__((address_space(1))) unsigned int*)(g),        \
      (__attribute__((address_space(3))) unsigned int*)(l), 16, 0, 0)

__device__ __forceinline__ unsigned short f2b(float f) {
  union { __hip_bfloat16 h; unsigned short u; } c;
  c.h = __float2bfloat16(f);
  return c.u;
}
__device__ __forceinline__ float b2f(unsigned short u) {
  union { unsigned short u; __hip_bfloat16 h; } c;
  c.u = u;
  return __bfloat162float(c.h);
}

// ---------------------------------------------------------------------------
// Kernel 1: fp32 -> bf16 conversion for x, Wq, Wk, Wv, Wo (float4 vectorized)
// regions (in float4 units): x 2097152, then 4 weights of 1048576 each
// ---------------------------------------------------------------------------
__global__ __launch_bounds__(256) void cvt_all(
    const float* __restrict__ x, const float* __restrict__ wq,
    const float* __restrict__ wk, const float* __restrict__ wv,
    const float* __restrict__ wo, unsigned short* __restrict__ xb,
    unsigned short* __restrict__ wqb, unsigned short* __restrict__ wkb,
    unsigned short* __restrict__ wvb, unsigned short* __restrict__ wob) {
  long i = (long)blockIdx.x * 256 + threadIdx.x;  // float4 index
  const float* src;
  unsigned short* dst;
  long off;
  if (i < 2097152) {
    src = x; dst = xb; off = i;
  } else {
    long j = i - 2097152;
    int wsel = (int)(j >> 20);
    off = j & 1048575;
    src = (wsel == 0) ? wq : (wsel == 1) ? wk : (wsel == 2) ? wv : wo;
    dst = (wsel == 0) ? wqb : (wsel == 1) ? wkb : (wsel == 2) ? wvb : wob;
  }
  float4 v = reinterpret_cast<const float4*>(src)[off];
  unsigned long long pk = (unsigned long long)f2b(v.x) |
                          ((unsigned long long)f2b(v.y) << 16) |
                          ((unsigned long long)f2b(v.z) << 32) |
                          ((unsigned long long)f2b(v.w) << 48);
  reinterpret_cast<unsigned long long*>(dst)[off] = pk;
}

// ---------------------------------------------------------------------------
// Kernel 2: C = A @ B^T  (A: MxK bf16, B: NxK bf16 row-major, C: MxN OutT)
// m97 structure: 128x128 tile, BK=32, global_load_lds(16B), 2 barriers/K-step
// blockIdx.z selects among 3 (B, C) pairs so QKV is one launch.
// ---------------------------------------------------------------------------
template <typename OutT>
__global__ __launch_bounds__(256) void gemm_bt(
    const unsigned short* __restrict__ A, const unsigned short* __restrict__ B0,
    const unsigned short* __restrict__ B1, const unsigned short* __restrict__ B2,
    OutT* __restrict__ C0, OutT* __restrict__ C1, OutT* __restrict__ C2,
    int M, int N, int K) {
  const unsigned short* B = (blockIdx.z == 0) ? B0 : (blockIdx.z == 1) ? B1 : B2;
  OutT* C = (blockIdx.z == 0) ? C0 : (blockIdx.z == 1) ? C1 : C2;

  __shared__ __align__(16) unsigned short sA[128 * 32];
  __shared__ __align__(16) unsigned short sB[128 * 32];

  const int t = threadIdx.x;
  const int w = t >> 6;
  const int lane = t & 63;
  const int l16 = lane & 15;
  const int lhi = lane >> 4;
  const int mbase = blockIdx.y * 128;
  const int nbase = blockIdx.x * 128;
  const int wm = w >> 1, wn = w & 1;

  // staging: thread t loads 8 bf16 at (row = t/4 [+64], k = (t%4)*8)
  const int srow = t >> 2;
  const int sk = (t & 3) * 8;
  const unsigned short* Asrc = A + (long)(mbase + srow) * K + sk;
  const unsigned short* Bsrc = B + (long)(nbase + srow) * K + sk;
  unsigned short* sAb = sA + w * 512;  // wave-uniform LDS base (+lane*16B by HW)
  unsigned short* sBb = sB + w * 512;

  f32x4 acc[4][4] = {};

  for (int kb = 0; kb < K; kb += 32) {
    GLDS16(Asrc + kb, sAb);
    GLDS16(Asrc + (long)64 * K + kb, sAb + 2048);
    GLDS16(Bsrc + kb, sBb);
    GLDS16(Bsrc + (long)64 * K + kb, sBb + 2048);
    __syncthreads();  // drains vmcnt: LDS tiles complete
    short8 af[4], bfr[4];
#pragma unroll
    for (int i = 0; i < 4; ++i) {
      af[i]  = *(const short8*)&sA[(wm * 64 + i * 16 + l16) * 32 + lhi * 8];
      bfr[i] = *(const short8*)&sB[(wn * 64 + i * 16 + l16) * 32 + lhi * 8];
    }
#pragma unroll
    for (int mi = 0; mi < 4; ++mi)
#pragma unroll
      for (int ni = 0; ni < 4; ++ni)
        acc[mi][ni] = __builtin_amdgcn_mfma_f32_16x16x32_bf16(
            af[mi], bfr[ni], acc[mi][ni], 0, 0, 0);
    __syncthreads();  // protect LDS from next iteration's staging
  }

#pragma unroll
  for (int mi = 0; mi < 4; ++mi)
#pragma unroll
    for (int ni = 0; ni < 4; ++ni)
#pragma unroll
      for (int r = 0; r < 4; ++r) {
        int row = mbase + wm * 64 + mi * 16 + lhi * 4 + r;  // C/D: row=(lane>>4)*4+r
        int col = nbase + wn * 64 + ni * 16 + l16;          //      col=lane&15
        float v = acc[mi][ni][r];
        if constexpr (sizeof(OutT) == 2)
          C[(long)row * N + col] = (OutT)f2b(v);
        else
          C[(long)row * N + col] = v;
      }
}

// ---------------------------------------------------------------------------
// Kernel 3: RoPE on Q and K in place (bf16). Pair (2i,2i+1) within each head.
// One thread per (s, h, i) pair; shares sincos between Q and K.
// ---------------------------------------------------------------------------
__global__ __launch_bounds__(256) void rope_qk(unsigned short* __restrict__ Q,
                                               unsigned short* __restrict__ K,
                                               const int* __restrict__ pos) {
  int t = blockIdx.x * 256 + threadIdx.x;  // 4096*16*64 threads
  int s = t >> 10;
  int idx = t & 1023;
  int h = idx >> 6;
  int i = idx & 63;
  long o = (long)s * 2048 + h * 128 + 2 * i;
  float p = (float)pos[s];
  // inv_freq = 10000^(-i/64) = 2^(-i * log2(10000)/64)
  float fr = exp2f(-0.20762050593046014f * (float)i);
  float ang = p * fr;
  float sn, cs;
  sincosf(ang, &sn, &cs);

  unsigned int qp = *reinterpret_cast<unsigned int*>(Q + o);
  float q1 = b2f((unsigned short)(qp & 0xffff));
  float q2 = b2f((unsigned short)(qp >> 16));
  unsigned int qo = (unsigned int)f2b(q1 * cs - q2 * sn) |
                    ((unsigned int)f2b(q1 * sn + q2 * cs) << 16);
  *reinterpret_cast<unsigned int*>(Q + o) = qo;

  unsigned int kp = *reinterpret_cast<unsigned int*>(K + o);
  float k1 = b2f((unsigned short)(kp & 0xffff));
  float k2 = b2f((unsigned short)(kp >> 16));
  unsigned int ko = (unsigned int)f2b(k1 * cs - k2 * sn) |
                    ((unsigned int)f2b(k1 * sn + k2 * cs) << 16);
  *reinterpret_cast<unsigned int*>(K + o) = ko;
}

// ---------------------------------------------------------------------------
// Kernel 4: V (4096x2048) -> VT (2048x4096), 64x64 LDS tile transpose
// ---------------------------------------------------------------------------
__global__ __launch_bounds__(256) void transpose_v(
    const unsigned short* __restrict__ V, unsigned short* __restrict__ VT) {
  __shared__ unsigned short tile[64][65];
  int t = threadIdx.x;
  int sb = blockIdx.y * 64;  // s block
  int cb = blockIdx.x * 64;  // col (h*128+d) block
#pragma unroll
  for (int i = 0; i < 16; ++i) {
    int idx = i * 256 + t;
    int r = idx >> 6, c = idx & 63;
    tile[r][c] = V[(long)(sb + r) * 2048 + cb + c];
  }
  __syncthreads();
#pragma unroll
  for (int i = 0; i < 16; ++i) {
    int idx = i * 256 + t;
    int r = idx >> 6, c = idx & 63;
    VT[(long)(cb + r) * 4096 + sb + c] = tile[c][r];
  }
}

// ---------------------------------------------------------------------------
// Kernel 5: causal flash attention, bf16 MFMA, fp32 online softmax.
// grid (S/64, H); 4 waves/block, each wave owns 16 q-rows; waves independent.
// Q,K: (S, 2048) bf16 (RoPE'd); VT: (2048, S) bf16; AO: (S, 2048) bf16.
// ---------------------------------------------------------------------------
__global__ __launch_bounds__(256) void attn_kernel(
    const unsigned short* __restrict__ Q, const unsigned short* __restrict__ K,
    const unsigned short* __restrict__ VT, unsigned short* __restrict__ AO) {
  __shared__ __align__(16) unsigned short sP[4][16][72];  // per-wave P buffer
  const int t = threadIdx.x;
  const int w = t >> 6;
  const int lane = t & 63;
  const int l16 = lane & 15;
  const int lhi = lane >> 4;
  const int head = blockIdx.y;
  const int qrow0 = blockIdx.x * 64 + w * 16;
  const int D = 2048, S = 4096;
  const float scale = 0.08838834764831845f;  // 1/sqrt(128)

  // Q fragments: row = lane&15, k(d) = (lane>>4)*8 + j, 4 chunks of K=32
  short8 qf[4];
#pragma unroll
  for (int kc = 0; kc < 4; ++kc)
    qf[kc] = *(const short8*)&Q[(long)(qrow0 + l16) * D + head * 128 + kc * 32 + lhi * 8];

  f32x4 of[8] = {};  // O accumulator: 8 d-tiles of 16, rows lhi*4+r
  float m[4], l[4];
#pragma unroll
  for (int r = 0; r < 4; ++r) { m[r] = -1e30f; l[r] = 0.f; }

  const int ntiles = blockIdx.x + 1;  // uniform across waves (KVBLK=QBLK=64)
  for (int kt = 0; kt < ntiles; ++kt) {
    const int kv0 = kt * 64;
    // ---- S = Q @ K^T (16 x 64), 4 col-subtiles x 4 d-chunks
    f32x4 sc[4] = {};
#pragma unroll
    for (int c = 0; c < 4; ++c)
#pragma unroll
      for (int kc = 0; kc < 4; ++kc) {
        short8 kf = *(const short8*)&K[(long)(kv0 + c * 16 + l16) * D +
                                       head * 128 + kc * 32 + lhi * 8];
        sc[c] = __builtin_amdgcn_mfma_f32_16x16x32_bf16(qf[kc], kf, sc[c], 0, 0, 0);
      }
    // ---- scale (+ causal mask on the last tile only)
    if (kt == ntiles - 1) {
#pragma unroll
      for (int c = 0; c < 4; ++c)
#pragma unroll
        for (int r = 0; r < 4; ++r) {
          int q = qrow0 + lhi * 4 + r;
          int kv = kv0 + c * 16 + l16;
          sc[c][r] = (kv > q) ? -1e30f : sc[c][r] * scale;
        }
    } else {
#pragma unroll
      for (int c = 0; c < 4; ++c)
#pragma unroll
        for (int r = 0; r < 4; ++r) sc[c][r] *= scale;
    }
    // ---- row max (butterfly over the 16 lanes holding the row)
    float tm[4];
#pragma unroll
    for (int r = 0; r < 4; ++r) {
      float v = fmaxf(fmaxf(sc[0][r], sc[1][r]), fmaxf(sc[2][r], sc[3][r]));
      v = fmaxf(v, __shfl_xor(v, 1));
      v = fmaxf(v, __shfl_xor(v, 2));
      v = fmaxf(v, __shfl_xor(v, 4));
      v = fmaxf(v, __shfl_xor(v, 8));
      tm[r] = v;
    }
    // ---- online-softmax rescale
#pragma unroll
    for (int r = 0; r < 4; ++r) {
      float mn = fmaxf(m[r], tm[r]);
      float f = __expf(m[r] - mn);
      m[r] = mn;
      l[r] *= f;
#pragma unroll
      for (int dt = 0; dt < 8; ++dt) of[dt][r] *= f;
    }
    // ---- P = exp(S - m), row sums, write P to LDS (row-major 16x64, stride 72)
    float ps[4] = {0.f, 0.f, 0.f, 0.f};
#pragma unroll
    for (int c = 0; c < 4; ++c)
#pragma unroll
      for (int r = 0; r < 4; ++r) {
        float p = __expf(sc[c][r] - m[r]);
        ps[r] += p;
        sP[w][lhi * 4 + r][c * 16 + l16] = f2b(p);
      }
#pragma unroll
    for (int r = 0; r < 4; ++r) {
      float v = ps[r];
      v += __shfl_xor(v, 1);
      v += __shfl_xor(v, 2);
      v += __shfl_xor(v, 4);
      v += __shfl_xor(v, 8);
      l[r] += v;
    }
    // ---- read P as A-fragments (wave-local LDS; compiler orders lgkmcnt)
    short8 pa[2];
#pragma unroll
    for (int kc2 = 0; kc2 < 2; ++kc2)
      pa[kc2] = *(const short8*)&sP[w][l16][kc2 * 32 + lhi * 8];
    // ---- O += P @ V   (B-frags from VT: col=d, k=kv contiguous)
#pragma unroll
    for (int dt = 0; dt < 8; ++dt)
#pragma unroll
      for (int kc2 = 0; kc2 < 2; ++kc2) {
        short8 vf = *(const short8*)&VT[(long)(head * 128 + dt * 16 + l16) * S +
                                        kv0 + kc2 * 32 + lhi * 8];
        of[dt] = __builtin_amdgcn_mfma_f32_16x16x32_bf16(pa[kc2], vf, of[dt], 0, 0, 0);
      }
  }
  // ---- normalize and store bf16
#pragma unroll
  for (int r = 0; r < 4; ++r) {
    float rinv = 1.0f / l[r];
#pragma unroll
    for (int dt = 0; dt < 8; ++dt)
      AO[(long)(qrow0 + lhi * 4 + r) * D + head * 128 + dt * 16 + l16] =
          f2b(of[dt][r] * rinv);
  }
}

// ---------------------------------------------------------------------------
extern "C" void kernel_launch(void* const* d_in, const int* in_sizes, int n_in,
                              void* d_out, int out_size, void* d_ws,
                              size_t ws_size, hipStream_t stream) {
  const float* x = (const float*)d_in[0];
  const int* pos = (const int*)d_in[1];
  const float* wq = (const float*)d_in[2];
  const float* wk = (const float*)d_in[3];
  const float* wv = (const float*)d_in[4];
  const float* wo = (const float*)d_in[5];
  float* out = (float*)d_out;

  char* ws = (char*)d_ws;
  const size_t MB = 1u << 20;
  unsigned short* xb  = (unsigned short*)(ws + 0 * MB);    // 16 MB
  unsigned short* wqb = (unsigned short*)(ws + 16 * MB);   // 8 MB
  unsigned short* wkb = (unsigned short*)(ws + 24 * MB);   // 8 MB
  unsigned short* wvb = (unsigned short*)(ws + 32 * MB);   // 8 MB
  unsigned short* wob = (unsigned short*)(ws + 40 * MB);   // 8 MB
  unsigned short* Qb  = (unsigned short*)(ws + 48 * MB);   // 16 MB
  unsigned short* Kb  = (unsigned short*)(ws + 64 * MB);   // 16 MB
  unsigned short* Vb  = (unsigned short*)(ws + 80 * MB);   // 16 MB
  unsigned short* VTb = (unsigned short*)(ws + 96 * MB);   // 16 MB
  unsigned short* AOb = (unsigned short*)(ws + 112 * MB);  // 16 MB

  // 1) fp32 -> bf16
  cvt_all<<<24576, 256, 0, stream>>>(x, wq, wk, wv, wo, xb, wqb, wkb, wvb, wob);
  // 2) Q,K,V = x @ W^T  (one launch, z selects weight/output)
  gemm_bt<unsigned short><<<dim3(16, 32, 3), 256, 0, stream>>>(
      xb, wqb, wkb, wvb, Qb, Kb, Vb, 4096, 2048, 2048);
  // 3) RoPE on Q,K
  rope_qk<<<16384, 256, 0, stream>>>(Qb, Kb, pos);
  // 4) V -> V^T (per-column layout for PV B-fragments)
  transpose_v<<<dim3(32, 64), 256, 0, stream>>>(Vb, VTb);
  // 5) causal flash attention
  attn_kernel<<<dim3(64, 16), 256, 0, stream>>>(Qb, Kb, VTb, AOb);
  // 6) out = AO @ Wo^T (fp32 out)
  gemm_bt<float><<<dim3(16, 32, 1), 256, 0, stream>>>(
      AOb, wob, wob, wob, out, out, out, 4096, 2048, 2048);
}

// Round 5
// 585.346 us; speedup vs baseline: 2.2822x; 2.2822x over previous
//
#include <hip/hip_runtime.h>
#include <hip/hip_bf16.h>

typedef __attribute__((ext_vector_type(8))) short short8;
typedef __attribute__((ext_vector_type(4))) float f32x4;

#define GLDS16(g, l)                                                     \
  __builtin_amdgcn_global_load_lds(                                      \
      (const __attribute__((address_space(1))) unsigned int*)(g),        \
      (__attribute__((address_space(3))) unsigned int*)(l), 16, 0, 0)

__device__ __forceinline__ unsigned short f2b(float f) {
  union { __hip_bfloat16 h; unsigned short u; } c;
  c.h = __float2bfloat16(f);
  return c.u;
}
__device__ __forceinline__ float b2f(unsigned short u) {
  union { unsigned short u; __hip_bfloat16 h; } c;
  c.u = u;
  return __bfloat162float(c.h);
}

// ---------------------------------------------------------------------------
// Kernel 1: fp32 -> bf16 conversion for x, Wq, Wk, Wv, Wo (float4 vectorized)
// ---------------------------------------------------------------------------
__global__ __launch_bounds__(256) void cvt_all(
    const float* __restrict__ x, const float* __restrict__ wq,
    const float* __restrict__ wk, const float* __restrict__ wv,
    const float* __restrict__ wo, unsigned short* __restrict__ xb,
    unsigned short* __restrict__ wqb, unsigned short* __restrict__ wkb,
    unsigned short* __restrict__ wvb, unsigned short* __restrict__ wob) {
  long i = (long)blockIdx.x * 256 + threadIdx.x;  // float4 index
  const float* src;
  unsigned short* dst;
  long off;
  if (i < 2097152) {
    src = x; dst = xb; off = i;
  } else {
    long j = i - 2097152;
    int wsel = (int)(j >> 20);
    off = j & 1048575;
    src = (wsel == 0) ? wq : (wsel == 1) ? wk : (wsel == 2) ? wv : wo;
    dst = (wsel == 0) ? wqb : (wsel == 1) ? wkb : (wsel == 2) ? wvb : wob;
  }
  float4 v = reinterpret_cast<const float4*>(src)[off];
  unsigned long long pk = (unsigned long long)f2b(v.x) |
                          ((unsigned long long)f2b(v.y) << 16) |
                          ((unsigned long long)f2b(v.z) << 32) |
                          ((unsigned long long)f2b(v.w) << 48);
  reinterpret_cast<unsigned long long*>(dst)[off] = pk;
}

// ---------------------------------------------------------------------------
// Kernel 2: C = A @ B^T  (m97 structure, unchanged this round)
// ---------------------------------------------------------------------------
template <typename OutT>
__global__ __launch_bounds__(256) void gemm_bt(
    const unsigned short* __restrict__ A, const unsigned short* __restrict__ B0,
    const unsigned short* __restrict__ B1, const unsigned short* __restrict__ B2,
    OutT* __restrict__ C0, OutT* __restrict__ C1, OutT* __restrict__ C2,
    int M, int N, int K) {
  const unsigned short* B = (blockIdx.z == 0) ? B0 : (blockIdx.z == 1) ? B1 : B2;
  OutT* C = (blockIdx.z == 0) ? C0 : (blockIdx.z == 1) ? C1 : C2;

  __shared__ __align__(16) unsigned short sA[128 * 32];
  __shared__ __align__(16) unsigned short sB[128 * 32];

  const int t = threadIdx.x;
  const int w = t >> 6;
  const int lane = t & 63;
  const int l16 = lane & 15;
  const int lhi = lane >> 4;
  const int mbase = blockIdx.y * 128;
  const int nbase = blockIdx.x * 128;
  const int wm = w >> 1, wn = w & 1;

  const int srow = t >> 2;
  const int sk = (t & 3) * 8;
  const unsigned short* Asrc = A + (long)(mbase + srow) * K + sk;
  const unsigned short* Bsrc = B + (long)(nbase + srow) * K + sk;
  unsigned short* sAb = sA + w * 512;
  unsigned short* sBb = sB + w * 512;

  f32x4 acc[4][4] = {};

  for (int kb = 0; kb < K; kb += 32) {
    GLDS16(Asrc + kb, sAb);
    GLDS16(Asrc + (long)64 * K + kb, sAb + 2048);
    GLDS16(Bsrc + kb, sBb);
    GLDS16(Bsrc + (long)64 * K + kb, sBb + 2048);
    __syncthreads();
    short8 af[4], bfr[4];
#pragma unroll
    for (int i = 0; i < 4; ++i) {
      af[i]  = *(const short8*)&sA[(wm * 64 + i * 16 + l16) * 32 + lhi * 8];
      bfr[i] = *(const short8*)&sB[(wn * 64 + i * 16 + l16) * 32 + lhi * 8];
    }
#pragma unroll
    for (int mi = 0; mi < 4; ++mi)
#pragma unroll
      for (int ni = 0; ni < 4; ++ni)
        acc[mi][ni] = __builtin_amdgcn_mfma_f32_16x16x32_bf16(
            af[mi], bfr[ni], acc[mi][ni], 0, 0, 0);
    __syncthreads();
  }

#pragma unroll
  for (int mi = 0; mi < 4; ++mi)
#pragma unroll
    for (int ni = 0; ni < 4; ++ni)
#pragma unroll
      for (int r = 0; r < 4; ++r) {
        int row = mbase + wm * 64 + mi * 16 + lhi * 4 + r;
        int col = nbase + wn * 64 + ni * 16 + l16;
        float v = acc[mi][ni][r];
        if constexpr (sizeof(OutT) == 2)
          C[(long)row * N + col] = (OutT)f2b(v);
        else
          C[(long)row * N + col] = v;
      }
}

// ---------------------------------------------------------------------------
// Kernel 3: RoPE on Q and K in place (bf16)
// ---------------------------------------------------------------------------
__global__ __launch_bounds__(256) void rope_qk(unsigned short* __restrict__ Q,
                                               unsigned short* __restrict__ K,
                                               const int* __restrict__ pos) {
  int t = blockIdx.x * 256 + threadIdx.x;
  int s = t >> 10;
  int idx = t & 1023;
  int h = idx >> 6;
  int i = idx & 63;
  long o = (long)s * 2048 + h * 128 + 2 * i;
  float p = (float)pos[s];
  float fr = exp2f(-0.20762050593046014f * (float)i);
  float ang = p * fr;
  float sn, cs;
  sincosf(ang, &sn, &cs);

  unsigned int qp = *reinterpret_cast<unsigned int*>(Q + o);
  float q1 = b2f((unsigned short)(qp & 0xffff));
  float q2 = b2f((unsigned short)(qp >> 16));
  unsigned int qo = (unsigned int)f2b(q1 * cs - q2 * sn) |
                    ((unsigned int)f2b(q1 * sn + q2 * cs) << 16);
  *reinterpret_cast<unsigned int*>(Q + o) = qo;

  unsigned int kp = *reinterpret_cast<unsigned int*>(K + o);
  float k1 = b2f((unsigned short)(kp & 0xffff));
  float k2 = b2f((unsigned short)(kp >> 16));
  unsigned int ko = (unsigned int)f2b(k1 * cs - k2 * sn) |
                    ((unsigned int)f2b(k1 * sn + k2 * cs) << 16);
  *reinterpret_cast<unsigned int*>(K + o) = ko;
}

// ---------------------------------------------------------------------------
// Kernel 4: V (4096x2048) -> VT (2048x4096)
// ---------------------------------------------------------------------------
__global__ __launch_bounds__(256) void transpose_v(
    const unsigned short* __restrict__ V, unsigned short* __restrict__ VT) {
  __shared__ unsigned short tile[64][65];
  int t = threadIdx.x;
  int sb = blockIdx.y * 64;
  int cb = blockIdx.x * 64;
#pragma unroll
  for (int i = 0; i < 16; ++i) {
    int idx = i * 256 + t;
    int r = idx >> 6, c = idx & 63;
    tile[r][c] = V[(long)(sb + r) * 2048 + cb + c];
  }
  __syncthreads();
#pragma unroll
  for (int i = 0; i < 16; ++i) {
    int idx = i * 256 + t;
    int r = idx >> 6, c = idx & 63;
    VT[(long)(cb + r) * 4096 + sb + c] = tile[c][r];
  }
}

// ---------------------------------------------------------------------------
// Kernel 5: causal flash attention — block-cooperative, LDS-staged, dbuf.
// grid (32, 16): qb = 31-bx (longest first), 4 waves x 32 q-rows = 128 rows.
// KVBLK=64. K tile [64][128] and VT tile [128][64] staged via global_load_lds
// with T2 XOR-swizzle (inverse-swizzled global source, swizzled ds_read).
// ---------------------------------------------------------------------------
__global__ __launch_bounds__(256, 2) void attn_kernel(
    const unsigned short* __restrict__ Q, const unsigned short* __restrict__ K,
    const unsigned short* __restrict__ VT, unsigned short* __restrict__ AO) {
  __shared__ __align__(16) unsigned short sK[2][64 * 128];  // 2 x 16 KB
  __shared__ __align__(16) unsigned short sV[2][128 * 64];  // 2 x 16 KB
  __shared__ __align__(16) unsigned short sP[4][16][72];    // 9 KB (per-wave)

  const int t = threadIdx.x;
  const int w = t >> 6;
  const int lane = t & 63;
  const int l16 = lane & 15;
  const int lhi = lane >> 4;
  const int head = blockIdx.y;
  const int qb = gridDim.x - 1 - blockIdx.x;  // longest-first dispatch
  const int qrow0 = qb * 128 + w * 32;
  const int D = 2048;
  const float scale = 0.08838834764831845f;  // 1/sqrt(128)

  // staging constants: per-thread source chunk-swizzle is constant across
  // rounds because (r*16)&7 == 0 / (r*32)&7 == 0.
  const int csK = (t & 15) ^ ((t >> 4) & 7);  // K: 16 chunks/row
  const int csV = (t & 7) ^ ((t >> 3) & 7);   // V: 8 chunks/row
  const unsigned short* Kst = K + (long)(t >> 4) * 2048 + head * 128 + csK * 8;
  const unsigned short* Vst = VT + (long)(head * 128 + (t >> 3)) * 4096 + csV * 8;
  const int wbase = w * 64;  // wave-uniform chunk base within a round

  // Q fragments: [mi][kc], row = lane&15, k = lhi*8+j
  short8 qf[2][4];
#pragma unroll
  for (int mi = 0; mi < 2; ++mi)
#pragma unroll
    for (int kc = 0; kc < 4; ++kc)
      qf[mi][kc] = *(const short8*)&Q[(long)(qrow0 + mi * 16 + l16) * D +
                                      head * 128 + kc * 32 + lhi * 8];

  f32x4 of[2][8] = {};
  float m[2][4], l[2][4];
#pragma unroll
  for (int mi = 0; mi < 2; ++mi)
#pragma unroll
    for (int r = 0; r < 4; ++r) { m[mi][r] = -1e30f; l[mi][r] = 0.f; }

  const int ntiles = 2 * (qb + 1);

  // ---- prologue: stage tile 0 into buffer 0
#pragma unroll
  for (int r = 0; r < 4; ++r) {
    GLDS16(Kst + (long)r * 16 * 2048, &sK[0][(r * 256 + wbase) * 8]);
    GLDS16(Vst + (long)r * 32 * 4096, &sV[0][(r * 256 + wbase) * 8]);
  }
  __syncthreads();

  int cur = 0;
  for (int kt = 0; kt < ntiles; ++kt) {
    const int kv0 = kt * 64;
    // ---- issue next-tile stage (overlaps with compute below; drained at
    //      the single __syncthreads at loop end)
    if (kt + 1 < ntiles) {
      const int nkv0 = kv0 + 64;
#pragma unroll
      for (int r = 0; r < 4; ++r) {
        GLDS16(Kst + (long)(nkv0 + r * 16) * 2048, &sK[cur ^ 1][(r * 256 + wbase) * 8]);
        GLDS16(Vst + (long)r * 32 * 4096 + nkv0, &sV[cur ^ 1][(r * 256 + wbase) * 8]);
      }
    }

    // ---- QK^T: 2 m-frags x 4 col-subtiles x 4 k-chunks (K-frag reused x2)
    f32x4 sc[2][4] = {};
#pragma unroll
    for (int c = 0; c < 4; ++c) {
      const int krow = c * 16 + l16;
#pragma unroll
      for (int kc = 0; kc < 4; ++kc) {
        const int kch = (kc * 4 + lhi) ^ (l16 & 7);
        short8 kf = *(const short8*)&sK[cur][krow * 128 + kch * 8];
        sc[0][c] = __builtin_amdgcn_mfma_f32_16x16x32_bf16(qf[0][kc], kf, sc[0][c], 0, 0, 0);
        sc[1][c] = __builtin_amdgcn_mfma_f32_16x16x32_bf16(qf[1][kc], kf, sc[1][c], 0, 0, 0);
      }
    }

    const bool anymask = (kv0 + 63 > qrow0);  // wave-uniform
    short8 pa[2][2];
#pragma unroll
    for (int mi = 0; mi < 2; ++mi) {
      // ---- scale + causal mask
      if (anymask) {
#pragma unroll
        for (int c = 0; c < 4; ++c)
#pragma unroll
          for (int r = 0; r < 4; ++r) {
            int q = qrow0 + mi * 16 + lhi * 4 + r;
            int kv = kv0 + c * 16 + l16;
            sc[mi][c][r] = (kv > q) ? -1e30f : sc[mi][c][r] * scale;
          }
      } else {
#pragma unroll
        for (int c = 0; c < 4; ++c)
#pragma unroll
          for (int r = 0; r < 4; ++r) sc[mi][c][r] *= scale;
      }
      // ---- row max (16-lane butterfly; row holders share lhi)
#pragma unroll
      for (int r = 0; r < 4; ++r) {
        float v = fmaxf(fmaxf(sc[mi][0][r], sc[mi][1][r]),
                        fmaxf(sc[mi][2][r], sc[mi][3][r]));
        v = fmaxf(v, __shfl_xor(v, 1));
        v = fmaxf(v, __shfl_xor(v, 2));
        v = fmaxf(v, __shfl_xor(v, 4));
        v = fmaxf(v, __shfl_xor(v, 8));
        float mn = fmaxf(m[mi][r], v);
        float f = __expf(m[mi][r] - mn);
        m[mi][r] = mn;
        l[mi][r] *= f;
#pragma unroll
        for (int dt = 0; dt < 8; ++dt) of[mi][dt][r] *= f;
      }
      // ---- P = exp(S-m): row sums + write to wave-private LDS
      float ps[4] = {0.f, 0.f, 0.f, 0.f};
#pragma unroll
      for (int c = 0; c < 4; ++c)
#pragma unroll
        for (int r = 0; r < 4; ++r) {
          float p = __expf(sc[mi][c][r] - m[mi][r]);
          ps[r] += p;
          sP[w][lhi * 4 + r][c * 16 + l16] = f2b(p);
        }
#pragma unroll
      for (int r = 0; r < 4; ++r) {
        float v = ps[r];
        v += __shfl_xor(v, 1);
        v += __shfl_xor(v, 2);
        v += __shfl_xor(v, 4);
        v += __shfl_xor(v, 8);
        l[mi][r] += v;
      }
      // ---- read back as A-fragments (compiler orders lgkm vs the writes)
#pragma unroll
      for (int kc2 = 0; kc2 < 2; ++kc2)
        pa[mi][kc2] = *(const short8*)&sP[w][l16][kc2 * 32 + lhi * 8];
    }

    // ---- O += P @ V (V-frag reused across both m-frags)
#pragma unroll
    for (int dt = 0; dt < 8; ++dt) {
      const int vrow = dt * 16 + l16;
#pragma unroll
      for (int kc2 = 0; kc2 < 2; ++kc2) {
        const int vch = (kc2 * 4 + lhi) ^ (l16 & 7);
        short8 vf = *(const short8*)&sV[cur][vrow * 64 + vch * 8];
        of[0][dt] = __builtin_amdgcn_mfma_f32_16x16x32_bf16(pa[0][kc2], vf, of[0][dt], 0, 0, 0);
        of[1][dt] = __builtin_amdgcn_mfma_f32_16x16x32_bf16(pa[1][kc2], vf, of[1][dt], 0, 0, 0);
      }
    }

    __syncthreads();  // drains vmcnt (next tile staged) + all LDS reads done
    cur ^= 1;
  }

  // ---- normalize and store
#pragma unroll
  for (int mi = 0; mi < 2; ++mi)
#pragma unroll
    for (int r = 0; r < 4; ++r) {
      float rinv = 1.0f / l[mi][r];
#pragma unroll
      for (int dt = 0; dt < 8; ++dt)
        AO[(long)(qrow0 + mi * 16 + lhi * 4 + r) * D + head * 128 + dt * 16 + l16] =
            f2b(of[mi][dt][r] * rinv);
    }
}

// ---------------------------------------------------------------------------
extern "C" void kernel_launch(void* const* d_in, const int* in_sizes, int n_in,
                              void* d_out, int out_size, void* d_ws,
                              size_t ws_size, hipStream_t stream) {
  const float* x = (const float*)d_in[0];
  const int* pos = (const int*)d_in[1];
  const float* wq = (const float*)d_in[2];
  const float* wk = (const float*)d_in[3];
  const float* wv = (const float*)d_in[4];
  const float* wo = (const float*)d_in[5];
  float* out = (float*)d_out;

  char* ws = (char*)d_ws;
  const size_t MB = 1u << 20;
  unsigned short* xb  = (unsigned short*)(ws + 0 * MB);
  unsigned short* wqb = (unsigned short*)(ws + 16 * MB);
  unsigned short* wkb = (unsigned short*)(ws + 24 * MB);
  unsigned short* wvb = (unsigned short*)(ws + 32 * MB);
  unsigned short* wob = (unsigned short*)(ws + 40 * MB);
  unsigned short* Qb  = (unsigned short*)(ws + 48 * MB);
  unsigned short* Kb  = (unsigned short*)(ws + 64 * MB);
  unsigned short* Vb  = (unsigned short*)(ws + 80 * MB);
  unsigned short* VTb = (unsigned short*)(ws + 96 * MB);
  unsigned short* AOb = (unsigned short*)(ws + 112 * MB);

  cvt_all<<<24576, 256, 0, stream>>>(x, wq, wk, wv, wo, xb, wqb, wkb, wvb, wob);
  gemm_bt<unsigned short><<<dim3(16, 32, 3), 256, 0, stream>>>(
      xb, wqb, wkb, wvb, Qb, Kb, Vb, 4096, 2048, 2048);
  rope_qk<<<16384, 256, 0, stream>>>(Qb, Kb, pos);
  transpose_v<<<dim3(32, 64), 256, 0, stream>>>(Vb, VTb);
  attn_kernel<<<dim3(32, 16), 256, 0, stream>>>(Qb, Kb, VTb, AOb);
  gemm_bt<float><<<dim3(16, 32, 1), 256, 0, stream>>>(
      AOb, wob, wob, wob, out, out, out, 4096, 2048, 2048);
}

// Round 9
// 534.800 us; speedup vs baseline: 2.4978x; 1.0945x over previous
//
#include <hip/hip_runtime.h>
#include <hip/hip_bf16.h>

typedef __attribute__((ext_vector_type(8))) short short8;
typedef __attribute__((ext_vector_type(4))) float f32x4;

#define GLDS16(g, l)                                                     \
  __builtin_amdgcn_global_load_lds(                                      \
      (const __attribute__((address_space(1))) unsigned int*)(g),        \
      (__attribute__((address_space(3))) unsigned int*)(l), 16, 0, 0)

__device__ __forceinline__ unsigned short f2b(float f) {
  union { __hip_bfloat16 h; unsigned short u; } c;
  c.h = __float2bfloat16(f);
  return c.u;
}
__device__ __forceinline__ float b2f(unsigned short u) {
  union { unsigned short u; __hip_bfloat16 h; } c;
  c.u = u;
  return __bfloat162float(c.h);
}

// ---------------------------------------------------------------------------
// Kernel 1: fp32 -> bf16 conversion for x, Wq, Wk, Wv, Wo (float4 vectorized)
// ---------------------------------------------------------------------------
__global__ __launch_bounds__(256) void cvt_all(
    const float* __restrict__ x, const float* __restrict__ wq,
    const float* __restrict__ wk, const float* __restrict__ wv,
    const float* __restrict__ wo, unsigned short* __restrict__ xb,
    unsigned short* __restrict__ wqb, unsigned short* __restrict__ wkb,
    unsigned short* __restrict__ wvb, unsigned short* __restrict__ wob) {
  long i = (long)blockIdx.x * 256 + threadIdx.x;  // float4 index
  const float* src;
  unsigned short* dst;
  long off;
  if (i < 2097152) {
    src = x; dst = xb; off = i;
  } else {
    long j = i - 2097152;
    int wsel = (int)(j >> 20);
    off = j & 1048575;
    src = (wsel == 0) ? wq : (wsel == 1) ? wk : (wsel == 2) ? wv : wo;
    dst = (wsel == 0) ? wqb : (wsel == 1) ? wkb : (wsel == 2) ? wvb : wob;
  }
  float4 v = reinterpret_cast<const float4*>(src)[off];
  unsigned long long pk = (unsigned long long)f2b(v.x) |
                          ((unsigned long long)f2b(v.y) << 16) |
                          ((unsigned long long)f2b(v.z) << 32) |
                          ((unsigned long long)f2b(v.w) << 48);
  reinterpret_cast<unsigned long long*>(dst)[off] = pk;
}

// ---------------------------------------------------------------------------
// Kernel 2: C = A @ B^T  (m97 structure, unchanged this round)
// ---------------------------------------------------------------------------
template <typename OutT>
__global__ __launch_bounds__(256) void gemm_bt(
    const unsigned short* __restrict__ A, const unsigned short* __restrict__ B0,
    const unsigned short* __restrict__ B1, const unsigned short* __restrict__ B2,
    OutT* __restrict__ C0, OutT* __restrict__ C1, OutT* __restrict__ C2,
    int M, int N, int K) {
  const unsigned short* B = (blockIdx.z == 0) ? B0 : (blockIdx.z == 1) ? B1 : B2;
  OutT* C = (blockIdx.z == 0) ? C0 : (blockIdx.z == 1) ? C1 : C2;

  __shared__ __align__(16) unsigned short sA[128 * 32];
  __shared__ __align__(16) unsigned short sB[128 * 32];

  const int t = threadIdx.x;
  const int w = t >> 6;
  const int lane = t & 63;
  const int l16 = lane & 15;
  const int lhi = lane >> 4;
  const int mbase = blockIdx.y * 128;
  const int nbase = blockIdx.x * 128;
  const int wm = w >> 1, wn = w & 1;

  const int srow = t >> 2;
  const int sk = (t & 3) * 8;
  const unsigned short* Asrc = A + (long)(mbase + srow) * K + sk;
  const unsigned short* Bsrc = B + (long)(nbase + srow) * K + sk;
  unsigned short* sAb = sA + w * 512;
  unsigned short* sBb = sB + w * 512;

  f32x4 acc[4][4] = {};

  for (int kb = 0; kb < K; kb += 32) {
    GLDS16(Asrc + kb, sAb);
    GLDS16(Asrc + (long)64 * K + kb, sAb + 2048);
    GLDS16(Bsrc + kb, sBb);
    GLDS16(Bsrc + (long)64 * K + kb, sBb + 2048);
    __syncthreads();
    short8 af[4], bfr[4];
#pragma unroll
    for (int i = 0; i < 4; ++i) {
      af[i]  = *(const short8*)&sA[(wm * 64 + i * 16 + l16) * 32 + lhi * 8];
      bfr[i] = *(const short8*)&sB[(wn * 64 + i * 16 + l16) * 32 + lhi * 8];
    }
#pragma unroll
    for (int mi = 0; mi < 4; ++mi)
#pragma unroll
      for (int ni = 0; ni < 4; ++ni)
        acc[mi][ni] = __builtin_amdgcn_mfma_f32_16x16x32_bf16(
            af[mi], bfr[ni], acc[mi][ni], 0, 0, 0);
    __syncthreads();
  }

#pragma unroll
  for (int mi = 0; mi < 4; ++mi)
#pragma unroll
    for (int ni = 0; ni < 4; ++ni)
#pragma unroll
      for (int r = 0; r < 4; ++r) {
        int row = mbase + wm * 64 + mi * 16 + lhi * 4 + r;
        int col = nbase + wn * 64 + ni * 16 + l16;
        float v = acc[mi][ni][r];
        if constexpr (sizeof(OutT) == 2)
          C[(long)row * N + col] = (OutT)f2b(v);
        else
          C[(long)row * N + col] = v;
      }
}

// ---------------------------------------------------------------------------
// Kernel 3: RoPE on Q and K in place (bf16)
// ---------------------------------------------------------------------------
__global__ __launch_bounds__(256) void rope_qk(unsigned short* __restrict__ Q,
                                               unsigned short* __restrict__ K,
                                               const int* __restrict__ pos) {
  int t = blockIdx.x * 256 + threadIdx.x;
  int s = t >> 10;
  int idx = t & 1023;
  int h = idx >> 6;
  int i = idx & 63;
  long o = (long)s * 2048 + h * 128 + 2 * i;
  float p = (float)pos[s];
  float fr = exp2f(-0.20762050593046014f * (float)i);
  float ang = p * fr;
  float sn, cs;
  sincosf(ang, &sn, &cs);

  unsigned int qp = *reinterpret_cast<unsigned int*>(Q + o);
  float q1 = b2f((unsigned short)(qp & 0xffff));
  float q2 = b2f((unsigned short)(qp >> 16));
  unsigned int qo = (unsigned int)f2b(q1 * cs - q2 * sn) |
                    ((unsigned int)f2b(q1 * sn + q2 * cs) << 16);
  *reinterpret_cast<unsigned int*>(Q + o) = qo;

  unsigned int kp = *reinterpret_cast<unsigned int*>(K + o);
  float k1 = b2f((unsigned short)(kp & 0xffff));
  float k2 = b2f((unsigned short)(kp >> 16));
  unsigned int ko = (unsigned int)f2b(k1 * cs - k2 * sn) |
                    ((unsigned int)f2b(k1 * sn + k2 * cs) << 16);
  *reinterpret_cast<unsigned int*>(K + o) = ko;
}

// ---------------------------------------------------------------------------
// Kernel 4: V (4096x2048) -> VT (2048x4096)
// ---------------------------------------------------------------------------
__global__ __launch_bounds__(256) void transpose_v(
    const unsigned short* __restrict__ V, unsigned short* __restrict__ VT) {
  __shared__ unsigned short tile[64][65];
  int t = threadIdx.x;
  int sb = blockIdx.y * 64;
  int cb = blockIdx.x * 64;
#pragma unroll
  for (int i = 0; i < 16; ++i) {
    int idx = i * 256 + t;
    int r = idx >> 6, c = idx & 63;
    tile[r][c] = V[(long)(sb + r) * 2048 + cb + c];
  }
  __syncthreads();
#pragma unroll
  for (int i = 0; i < 16; ++i) {
    int idx = i * 256 + t;
    int r = idx >> 6, c = idx & 63;
    VT[(long)(cb + r) * 4096 + sb + c] = tile[c][r];
  }
}

// ---------------------------------------------------------------------------
// Kernel 5: causal flash attention — block-cooperative, LDS-staged, dbuf.
// Flat grid 512. In-kernel decode pins 2 heads per XCD (K+VT working set =
// 4 MB = L2 size) and gives co-resident CU block-pairs complementary qb
// (2(32-qi) + 2(qi+1) = 66 tile-iters, constant) to kill load imbalance.
// 4 waves x 32 q-rows = 128 rows/block; KVBLK=64; T2-swizzled LDS tiles.
// ---------------------------------------------------------------------------
__global__ __launch_bounds__(256, 2) void attn_kernel(
    const unsigned short* __restrict__ Q, const unsigned short* __restrict__ K,
    const unsigned short* __restrict__ VT, unsigned short* __restrict__ AO) {
  __shared__ __align__(16) unsigned short sK[2][64 * 128];  // 2 x 16 KB
  __shared__ __align__(16) unsigned short sV[2][128 * 64];  // 2 x 16 KB
  __shared__ __align__(16) unsigned short sP[4][16][72];    // 9 KB (per-wave)

  const int t = threadIdx.x;
  const int w = t >> 6;
  const int lane = t & 63;
  const int l16 = lane & 15;
  const int lhi = lane >> 4;

  // ---- work decode: XCD-clustered heads + complementary qb pairing
  const int fid = blockIdx.x;          // 0..511
  const int xcd = fid & 7;             // dispatch round-robins XCDs
  const int j = fid >> 3;              // 0..63 within XCD
  const int head = (xcd << 1) | (j & 1);  // 2 heads pinned per XCD
  const int qi = j >> 1;               // 0..31
  const int qb = (qi < 16) ? (31 - qi) : (qi - 16);  // long first; pairs sum 66

  const int qrow0 = qb * 128 + w * 32;
  const int D = 2048;
  const float scale = 0.08838834764831845f;  // 1/sqrt(128)

  // staging constants: per-thread source chunk-swizzle is constant across
  // rounds because (r*16)&7 == 0 / (r*32)&7 == 0.
  const int csK = (t & 15) ^ ((t >> 4) & 7);  // K: 16 chunks/row
  const int csV = (t & 7) ^ ((t >> 3) & 7);   // V: 8 chunks/row
  const unsigned short* Kst = K + (long)(t >> 4) * 2048 + head * 128 + csK * 8;
  const unsigned short* Vst = VT + (long)(head * 128 + (t >> 3)) * 4096 + csV * 8;
  const int wbase = w * 64;  // wave-uniform chunk base within a round

  // Q fragments: [mi][kc], row = lane&15, k = lhi*8+j
  short8 qf[2][4];
#pragma unroll
  for (int mi = 0; mi < 2; ++mi)
#pragma unroll
    for (int kc = 0; kc < 4; ++kc)
      qf[mi][kc] = *(const short8*)&Q[(long)(qrow0 + mi * 16 + l16) * D +
                                      head * 128 + kc * 32 + lhi * 8];

  f32x4 of[2][8] = {};
  float m[2][4], l[2][4];
#pragma unroll
  for (int mi = 0; mi < 2; ++mi)
#pragma unroll
    for (int r = 0; r < 4; ++r) { m[mi][r] = -1e30f; l[mi][r] = 0.f; }

  const int ntiles = 2 * (qb + 1);

  // ---- prologue: stage tile 0 into buffer 0
#pragma unroll
  for (int r = 0; r < 4; ++r) {
    GLDS16(Kst + (long)r * 16 * 2048, &sK[0][(r * 256 + wbase) * 8]);
    GLDS16(Vst + (long)r * 32 * 4096, &sV[0][(r * 256 + wbase) * 8]);
  }
  __syncthreads();

  int cur = 0;
  for (int kt = 0; kt < ntiles; ++kt) {
    const int kv0 = kt * 64;
    // ---- issue next-tile stage (overlaps with compute below; drained at
    //      the single __syncthreads at loop end)
    if (kt + 1 < ntiles) {
      const int nkv0 = kv0 + 64;
#pragma unroll
      for (int r = 0; r < 4; ++r) {
        GLDS16(Kst + (long)(nkv0 + r * 16) * 2048, &sK[cur ^ 1][(r * 256 + wbase) * 8]);
        GLDS16(Vst + (long)r * 32 * 4096 + nkv0, &sV[cur ^ 1][(r * 256 + wbase) * 8]);
      }
    }

    // ---- QK^T: 2 m-frags x 4 col-subtiles x 4 k-chunks (K-frag reused x2)
    f32x4 sc[2][4] = {};
#pragma unroll
    for (int c = 0; c < 4; ++c) {
      const int krow = c * 16 + l16;
#pragma unroll
      for (int kc = 0; kc < 4; ++kc) {
        const int kch = (kc * 4 + lhi) ^ (l16 & 7);
        short8 kf = *(const short8*)&sK[cur][krow * 128 + kch * 8];
        sc[0][c] = __builtin_amdgcn_mfma_f32_16x16x32_bf16(qf[0][kc], kf, sc[0][c], 0, 0, 0);
        sc[1][c] = __builtin_amdgcn_mfma_f32_16x16x32_bf16(qf[1][kc], kf, sc[1][c], 0, 0, 0);
      }
    }

    const bool anymask = (kv0 + 63 > qrow0);  // wave-uniform
    short8 pa[2][2];
#pragma unroll
    for (int mi = 0; mi < 2; ++mi) {
      // ---- scale + causal mask
      if (anymask) {
#pragma unroll
        for (int c = 0; c < 4; ++c)
#pragma unroll
          for (int r = 0; r < 4; ++r) {
            int q = qrow0 + mi * 16 + lhi * 4 + r;
            int kv = kv0 + c * 16 + l16;
            sc[mi][c][r] = (kv > q) ? -1e30f : sc[mi][c][r] * scale;
          }
      } else {
#pragma unroll
        for (int c = 0; c < 4; ++c)
#pragma unroll
          for (int r = 0; r < 4; ++r) sc[mi][c][r] *= scale;
      }
      // ---- row max (16-lane butterfly; row holders share lhi)
#pragma unroll
      for (int r = 0; r < 4; ++r) {
        float v = fmaxf(fmaxf(sc[mi][0][r], sc[mi][1][r]),
                        fmaxf(sc[mi][2][r], sc[mi][3][r]));
        v = fmaxf(v, __shfl_xor(v, 1));
        v = fmaxf(v, __shfl_xor(v, 2));
        v = fmaxf(v, __shfl_xor(v, 4));
        v = fmaxf(v, __shfl_xor(v, 8));
        float mn = fmaxf(m[mi][r], v);
        float f = __expf(m[mi][r] - mn);
        m[mi][r] = mn;
        l[mi][r] *= f;
#pragma unroll
        for (int dt = 0; dt < 8; ++dt) of[mi][dt][r] *= f;
      }
      // ---- P = exp(S-m): row sums + write to wave-private LDS
      float ps[4] = {0.f, 0.f, 0.f, 0.f};
#pragma unroll
      for (int c = 0; c < 4; ++c)
#pragma unroll
        for (int r = 0; r < 4; ++r) {
          float p = __expf(sc[mi][c][r] - m[mi][r]);
          ps[r] += p;
          sP[w][lhi * 4 + r][c * 16 + l16] = f2b(p);
        }
#pragma unroll
      for (int r = 0; r < 4; ++r) {
        float v = ps[r];
        v += __shfl_xor(v, 1);
        v += __shfl_xor(v, 2);
        v += __shfl_xor(v, 4);
        v += __shfl_xor(v, 8);
        l[mi][r] += v;
      }
      // ---- read back as A-fragments (compiler orders lgkm vs the writes)
#pragma unroll
      for (int kc2 = 0; kc2 < 2; ++kc2)
        pa[mi][kc2] = *(const short8*)&sP[w][l16][kc2 * 32 + lhi * 8];
    }

    // ---- O += P @ V (V-frag reused across both m-frags)
#pragma unroll
    for (int dt = 0; dt < 8; ++dt) {
      const int vrow = dt * 16 + l16;
#pragma unroll
      for (int kc2 = 0; kc2 < 2; ++kc2) {
        const int vch = (kc2 * 4 + lhi) ^ (l16 & 7);
        short8 vf = *(const short8*)&sV[cur][vrow * 64 + vch * 8];
        of[0][dt] = __builtin_amdgcn_mfma_f32_16x16x32_bf16(pa[0][kc2], vf, of[0][dt], 0, 0, 0);
        of[1][dt] = __builtin_amdgcn_mfma_f32_16x16x32_bf16(pa[1][kc2], vf, of[1][dt], 0, 0, 0);
      }
    }

    __syncthreads();  // drains vmcnt (next tile staged) + all LDS reads done
    cur ^= 1;
  }

  // ---- normalize and store
#pragma unroll
  for (int mi = 0; mi < 2; ++mi)
#pragma unroll
    for (int r = 0; r < 4; ++r) {
      float rinv = 1.0f / l[mi][r];
#pragma unroll
      for (int dt = 0; dt < 8; ++dt)
        AO[(long)(qrow0 + mi * 16 + lhi * 4 + r) * D + head * 128 + dt * 16 + l16] =
            f2b(of[mi][dt][r] * rinv);
    }
}

// ---------------------------------------------------------------------------
extern "C" void kernel_launch(void* const* d_in, const int* in_sizes, int n_in,
                              void* d_out, int out_size, void* d_ws,
                              size_t ws_size, hipStream_t stream) {
  const float* x = (const float*)d_in[0];
  const int* pos = (const int*)d_in[1];
  const float* wq = (const float*)d_in[2];
  const float* wk = (const float*)d_in[3];
  const float* wv = (const float*)d_in[4];
  const float* wo = (const float*)d_in[5];
  float* out = (float*)d_out;

  char* ws = (char*)d_ws;
  const size_t MB = 1u << 20;
  unsigned short* xb  = (unsigned short*)(ws + 0 * MB);
  unsigned short* wqb = (unsigned short*)(ws + 16 * MB);
  unsigned short* wkb = (unsigned short*)(ws + 24 * MB);
  unsigned short* wvb = (unsigned short*)(ws + 32 * MB);
  unsigned short* wob = (unsigned short*)(ws + 40 * MB);
  unsigned short* Qb  = (unsigned short*)(ws + 48 * MB);
  unsigned short* Kb  = (unsigned short*)(ws + 64 * MB);
  unsigned short* Vb  = (unsigned short*)(ws + 80 * MB);
  unsigned short* VTb = (unsigned short*)(ws + 96 * MB);
  unsigned short* AOb = (unsigned short*)(ws + 112 * MB);

  cvt_all<<<24576, 256, 0, stream>>>(x, wq, wk, wv, wo, xb, wqb, wkb, wvb, wob);
  gemm_bt<unsigned short><<<dim3(16, 32, 3), 256, 0, stream>>>(
      xb, wqb, wkb, wvb, Qb, Kb, Vb, 4096, 2048, 2048);
  rope_qk<<<16384, 256, 0, stream>>>(Qb, Kb, pos);
  transpose_v<<<dim3(32, 64), 256, 0, stream>>>(Vb, VTb);
  attn_kernel<<<512, 256, 0, stream>>>(Qb, Kb, VTb, AOb);
  gemm_bt<float><<<dim3(16, 32, 1), 256, 0, stream>>>(
      AOb, wob, wob, wob, out, out, out, 4096, 2048, 2048);
}